// Round 2
// baseline (865.235 us; speedup 1.0000x reference)
//
#include <hip/hip_runtime.h>
#include <math.h>

#define N_NODES 50000
#define N_EDGES 1600000
#define HIDDEN  128
#define DC      16      // number of RBF centers
#define EPB     64      // edges per block
#define BLOCK   256

// mu_k = k * 6/15 = k * 0.4   (linspace(0,6,16) is endpoint-inclusive!)
// sigma = (6-0)/16 = 0.375 -> inv_sigma = 8/3
#define MU_STEP   0.4f
#define INV_SIGMA 2.6666666666666665f

__device__ __forceinline__ float fast_sigmoid(float x) {
    float e = __expf(-x);                       // v_mul + v_exp_f32
    return __builtin_amdgcn_rcpf(1.0f + e);     // v_rcp_f32 (~1 ulp, fine at 2% tol)
}

__global__ __launch_bounds__(BLOCK, 4) void edge_attr_kernel(
    const float* __restrict__ pos,        // [N_NODES, 3]
    const int* __restrict__ ei,           // [2, N_EDGES] (harness delivers int32)
    const float* __restrict__ W,          // [DC, HIDDEN]
    const float* __restrict__ b,          // [HIDDEN]
    float* __restrict__ out)              // [N_EDGES, HIDDEN]
{
    // transposed rbf tile: rbf_s[k][e]  -> phase-1 writes stride-1 (no bank
    // conflicts), phase-2 reads are same-address broadcasts (free)
    __shared__ float rbf_s[DC][EPB];

    const int tid = threadIdx.x;
    const int h4  = tid & 31;   // which float4 chunk of the 128 hidden cols
    const int eo  = tid >> 5;   // 0..7 : edge-row offset within the block

    // ---- W columns into registers (L1-broadcast loads, 8 threads share addr)
    float4 wcol[DC];
    #pragma unroll
    for (int k = 0; k < DC; ++k)
        wcol[k] = *reinterpret_cast<const float4*>(W + k * HIDDEN + h4 * 4);
    const float4 bias = *reinterpret_cast<const float4*>(b + h4 * 4);

    // ---- Phase 1: RBF features for this block's 64 edges
    {
        const int el = tid & 63;          // edge within block
        const int kg = tid >> 6;          // 0..3 -> k = kg*4 .. kg*4+3
        const int e = blockIdx.x * EPB + el;
        const int s = ei[e];
        const int d = ei[N_EDGES + e];
        const float dx = pos[3 * s + 0] - pos[3 * d + 0];
        const float dy = pos[3 * s + 1] - pos[3 * d + 1];
        const float dz = pos[3 * s + 2] - pos[3 * d + 2];
        const float dist = sqrtf(dx * dx + dy * dy + dz * dz);
        #pragma unroll
        for (int j = 0; j < 4; ++j) {
            const int k = kg * 4 + j;
            const float t = (dist - MU_STEP * (float)k) * INV_SIGMA;
            rbf_s[k][el] = __expf(-t * t);
        }
    }
    __syncthreads();

    // ---- Phase 2: out[e][h] = sigmoid(sum_k rbf[k] * W[k][h] + b[h])
    const size_t row0 = (size_t)blockIdx.x * EPB;
    #pragma unroll
    for (int i = 0; i < EPB / 8; ++i) {
        const int el = eo + i * 8;

        float r[DC];
        #pragma unroll
        for (int k = 0; k < DC; ++k) r[k] = rbf_s[k][el];   // broadcast reads

        float4 acc = bias;
        #pragma unroll
        for (int k = 0; k < DC; ++k) {
            acc.x = fmaf(r[k], wcol[k].x, acc.x);
            acc.y = fmaf(r[k], wcol[k].y, acc.y);
            acc.z = fmaf(r[k], wcol[k].z, acc.z);
            acc.w = fmaf(r[k], wcol[k].w, acc.w);
        }
        acc.x = fast_sigmoid(acc.x);
        acc.y = fast_sigmoid(acc.y);
        acc.z = fast_sigmoid(acc.z);
        acc.w = fast_sigmoid(acc.w);

        // wave writes a contiguous 1 KB span (2 adjacent 512 B rows)
        *reinterpret_cast<float4*>(out + (row0 + el) * HIDDEN + h4 * 4) = acc;
    }
}

extern "C" void kernel_launch(void* const* d_in, const int* in_sizes, int n_in,
                              void* d_out, int out_size, void* d_ws, size_t ws_size,
                              hipStream_t stream) {
    const float* pos = (const float*)d_in[0];
    const int*   ei  = (const int*)d_in[1];     // harness delivers integers as int32
    const float* W   = (const float*)d_in[2];
    const float* b   = (const float*)d_in[3];
    float*       out = (float*)d_out;

    dim3 grid(N_EDGES / EPB);   // 1,600,000 / 64 = 25,000 blocks exactly
    edge_attr_kernel<<<grid, BLOCK, 0, stream>>>(pos, ei, W, b, out);
}